// Round 3
// baseline (403.497 us; speedup 1.0000x reference)
//
#include <hip/hip_runtime.h>
#include <stdint.h>

#define N_NODES    50000
#define K_MAX      10
#define BATCH      64
#define T_STEPS    32
#define N_INPUTS   16
#define INPUT_BITS 64

#define NPW   256                 // nodes per workgroup
#define NWG   196                 // ceil(50000/256) -- must be <= 256 CUs for coop
#define NTHR  1024                // 4 threads (batch quarters) per node

// ---------------- workspace layout (bytes) ----------------
#define OFF_BUF0   0u             // uint64[50001] state ping (+ zero sentinel)
#define OFF_BUF1   400128u        // uint64[50001] state pong
#define OFF_XMASK  800256u        // uint64[32*64] per-step input xor masks
#define OFF_CTR    816640u        // uint32[32] barrier counters (zeroed by prep)

// ---------------- prep: init transposed state, xor masks, barrier ctrs ----------------
__global__ void prep_kernel(const int* __restrict__ x,
                            const int* __restrict__ init_states,
                            const int* __restrict__ input_nodes,
                            uint64_t* __restrict__ buf0,
                            uint64_t* __restrict__ buf1,
                            uint64_t* __restrict__ xmask,
                            uint32_t* __restrict__ ctr) {
    int gid = blockIdx.x * blockDim.x + threadIdx.x;
    if (gid < N_NODES) {
        int n = gid;
        // last occurrence of n in input_nodes (last-write-wins scatter semantics)
        int jm = -1;
        for (int j = 0; j < INPUT_BITS; ++j)
            if (input_nodes[j] == n) jm = j;
        uint64_t v = init_states[n] ? ~0ull : 0ull;   // same init for all 64 batches
        if (jm >= 0) {
            uint64_t m = 0ull;
            for (int b = 0; b < BATCH; ++b)
                m |= (uint64_t)(x[b * (T_STEPS * INPUT_BITS) + jm] & 1) << b;  // t = 0
            v ^= m;
        }
        buf0[n] = v;
    } else if (gid == N_NODES) {
        buf0[N_NODES] = 0ull; buf1[N_NODES] = 0ull;   // zero sentinel for masked edges
    } else if (gid < N_NODES + 1 + T_STEPS * INPUT_BITS) {
        int k = gid - (N_NODES + 1);
        int t = k >> 6, j = k & 63;
        uint64_t m = 0ull;
        for (int b = 0; b < BATCH; ++b)
            m |= (uint64_t)(x[b * (T_STEPS * INPUT_BITS) + t * INPUT_BITS + j] & 1) << b;
        xmask[k] = m;
    } else {
        int c = gid - (N_NODES + 1 + T_STEPS * INPUT_BITS);
        if (c < T_STEPS) ctr[c] = 0;                  // replay-safe barrier counters
    }
}

// ---------------- cooperative kernel: pack LUT to LDS, run all 32 steps ----------------
__global__ __launch_bounds__(NTHR)
void reservoir_coop(const int* __restrict__ adj,
                    const int* __restrict__ adjmask,
                    const int* __restrict__ lut,
                    const int* __restrict__ input_nodes,
                    const uint64_t* __restrict__ xmask,
                    uint64_t* __restrict__ buf0,
                    uint64_t* __restrict__ buf1,
                    uint32_t* __restrict__ ctr) {
    __shared__ uint8_t lutb[NPW * 128];   // 32 KB: this WG's 256 bit-packed LUT rows

    const int tid  = threadIdx.x;
    const int lane = tid & 63;
    const int wv   = tid >> 6;            // 16 waves
    const int wg   = blockIdx.x;

    // ---- pack LUT rows straight into LDS (coalesced dword loads + ballot) ----
    for (int rr = 0; rr < 16; ++rr) {
        int r  = wv * 16 + rr;
        int gn = wg * NPW + r;
        if (gn < N_NODES) {
            uint64_t mine = 0ull;
            #pragma unroll
            for (int c = 0; c < 16; ++c) {
                int v = lut[(size_t)gn * 1024 + (size_t)c * 64 + lane];
                uint64_t m = __ballot(v & 1);
                if (lane == c) mine = m;      // lane c keeps word c
            }
            if (lane < 16) ((uint64_t*)lutb)[r * 16 + lane] = mine;
        }
    }

    // ---- persistent per-thread setup (lives in registers for all 32 steps) ----
    const int nl   = tid >> 2;            // local node
    const int q    = tid & 3;             // batch quarter (16 batches)
    const int node = wg * NPW + nl;
    const bool valid = node < N_NODES;
    const uint32_t qsh = (uint32_t)(q & 1) * 16;

    uint32_t off[K_MAX];                  // byte offsets of gather dwords
    uint32_t soff = 0;                    // store dword byte offset (even-q lanes)
    int jm = -1;
    if (valid) {
        #pragma unroll
        for (int k = 0; k < K_MAX; ++k) {
            int a  = adj[node * K_MAX + k];
            int mk = adjmask[node * K_MAX + k];
            // masked-off neighbor -> sentinel word N_NODES (always 0)
            off[k] = (uint32_t)(mk ? a : N_NODES) * 8u + (uint32_t)(q >> 1) * 4u;
        }
        for (int j = 0; j < INPUT_BITS; ++j)
            if (input_nodes[j] == node) jm = j;   // last occurrence
        soff = (uint32_t)node * 8u + (uint32_t)(q >> 1) * 4u;
    }
    const int rowbase = nl * 128;
    __syncthreads();                      // LDS pack complete

    uint64_t* cur = buf0;
    uint64_t* nxt = buf1;

    for (int t = 0; t < T_STEPS; ++t) {
        if (valid) {
            const char* src = (const char*)cur;
            uint32_t w[K_MAX];
            // agent-scope loads bypass non-coherent L2s (coherence point = L3)
            #pragma unroll
            for (int k = 0; k < K_MAX; ++k)
                w[k] = __hip_atomic_load((const uint32_t*)(src + off[k]),
                                         __ATOMIC_RELAXED, __HIP_MEMORY_SCOPE_AGENT) >> qsh;

            uint32_t o16 = 0;
            #pragma unroll
            for (int b = 0; b < 16; ++b) {
                uint32_t idx = 0;
                #pragma unroll
                for (int k = 0; k < K_MAX; ++k)
                    idx = (idx << 1) | ((w[k] >> b) & 1u);   // k=0 -> MSB (pow2 order)
                uint32_t d = *(const uint32_t*)(lutb + rowbase + ((idx >> 5) << 2));
                o16 |= ((d >> (idx & 31)) & 1u) << b;
            }

            // pair lanes (q even/odd) combine to one dword store
            uint32_t hi = __shfl_down(o16, 1);
            if ((q & 1) == 0) {
                uint32_t o32 = o16 | (hi << 16);
                // fold next step's input-bit XOR into this write
                if (jm >= 0 && t < T_STEPS - 1)
                    o32 ^= ((const uint32_t*)xmask)[((t + 1) * INPUT_BITS + jm) * 2 + (q >> 1)];
                __hip_atomic_store((uint32_t*)((char*)nxt + soff), o32,
                                   __ATOMIC_RELAXED, __HIP_MEMORY_SCOPE_AGENT);
            }
        }

        // ---- global barrier: syncthreads drains vmcnt; 1 atomic + poll per WG ----
        __syncthreads();
        if (tid == 0) {
            __hip_atomic_fetch_add(&ctr[t], 1u, __ATOMIC_RELAXED, __HIP_MEMORY_SCOPE_AGENT);
            while (__hip_atomic_load(&ctr[t], __ATOMIC_RELAXED, __HIP_MEMORY_SCOPE_AGENT) < (uint32_t)NWG)
                __builtin_amdgcn_s_sleep(2);
        }
        __syncthreads();
        asm volatile("" ::: "memory");

        uint64_t* tmp = cur; cur = nxt; nxt = tmp;
    }
}

// ---------------- output: out[b,i] = sum_n state[b,n]*W[i,n] + bias[i] ----------------
__global__ void out_kernel(const uint64_t* __restrict__ fstate,
                           const float* __restrict__ W,
                           const float* __restrict__ bias,
                           float* __restrict__ out) {
    const int wg = blockIdx.x;          // b*16 + i
    const int b = wg >> 4, i = wg & 15;
    const int tid = threadIdx.x;
    const uint8_t* st = (const uint8_t*)fstate;
    const int byteoff = b >> 3, bsh = b & 7;

    float s = 0.f;
    for (int n = tid; n < N_NODES; n += 256) {
        uint32_t bit = (st[(size_t)n * 8 + byteoff] >> bsh) & 1u;
        s += (float)bit * W[(size_t)i * N_NODES + n];
    }
    #pragma unroll
    for (int off = 32; off; off >>= 1) s += __shfl_down(s, off);

    __shared__ float part[4];
    const int lane = tid & 63, wave = tid >> 6;
    if (lane == 0) part[wave] = s;
    __syncthreads();
    if (tid == 0) out[wg] = part[0] + part[1] + part[2] + part[3] + bias[i];
}

extern "C" void kernel_launch(void* const* d_in, const int* in_sizes, int n_in,
                              void* d_out, int out_size, void* d_ws, size_t ws_size,
                              hipStream_t stream) {
    const int*   x       = (const int*)d_in[0];
    const int*   adj     = (const int*)d_in[1];
    const int*   adjmask = (const int*)d_in[2];
    const int*   lut     = (const int*)d_in[3];
    const int*   initst  = (const int*)d_in[4];
    const int*   innodes = (const int*)d_in[5];
    const float* W       = (const float*)d_in[6];
    const float* bias    = (const float*)d_in[7];
    float* out = (float*)d_out;

    char* ws = (char*)d_ws;
    uint64_t* buf0  = (uint64_t*)(ws + OFF_BUF0);
    uint64_t* buf1  = (uint64_t*)(ws + OFF_BUF1);
    uint64_t* xmask = (uint64_t*)(ws + OFF_XMASK);
    uint32_t* ctr   = (uint32_t*)(ws + OFF_CTR);

    {
        int prep_threads = (N_NODES + 1) + T_STEPS * INPUT_BITS + T_STEPS;
        int prep_blocks = (prep_threads + 255) / 256;
        hipLaunchKernelGGL(prep_kernel, dim3(prep_blocks), dim3(256), 0, stream,
                           x, initst, innodes, buf0, buf1, xmask, ctr);
    }

    {
        void* args[] = { (void*)&adj, (void*)&adjmask, (void*)&lut, (void*)&innodes,
                         (void*)&xmask, (void*)&buf0, (void*)&buf1, (void*)&ctr };
        hipLaunchCooperativeKernel((void*)reservoir_coop,
                                   dim3(NWG), dim3(NTHR),
                                   args, 0, stream);
    }

    // 32 steps (even) -> final states in buf0
    hipLaunchKernelGGL(out_kernel, dim3(BATCH * N_INPUTS), dim3(256), 0, stream,
                       (const uint64_t*)buf0, W, bias, out);
}

// Round 4
// 388.750 us; speedup vs baseline: 1.0379x; 1.0379x over previous
//
#include <hip/hip_runtime.h>
#include <stdint.h>

#define N_NODES    50000
#define K_MAX      10
#define BATCH      64
#define T_STEPS    32
#define N_INPUTS   16
#define INPUT_BITS 64

#define NPW   256                 // nodes per workgroup
#define NWG   196                 // ceil(50000/256) <= 256 CUs (coop co-residency)
#define NTHR  1024                // 4 threads (batch quarters) per node
#define NBUF  (T_STEPS + 1)       // state ring: step t reads buf[t], writes buf[t+1]

#define BUF_STRIDE_B 400128u      // bytes per state buffer (50001*8 -> 128B aligned)

// ---------------- workspace layout (bytes) ----------------
#define OFF_BUFS   0u
#define OFF_XMASK  (NBUF * BUF_STRIDE_B)            // uint64[32*64]
#define OFF_CTR    (OFF_XMASK + 16384u)             // uint32[32] barrier counters
#define OFF_PLUT   (OFF_CTR + 128u)                 // uint8[50176*128] packed LUT (padded)
// total ~19.7 MB

// ---------------- prep: init state ring head, xor masks, sentinels, ctrs ----------------
__global__ void prep_kernel(const int* __restrict__ x,
                            const int* __restrict__ init_states,
                            const int* __restrict__ input_nodes,
                            uint64_t* __restrict__ bufs,     // ring base
                            uint64_t* __restrict__ xmask,
                            uint32_t* __restrict__ ctr) {
    const int gid = blockIdx.x * blockDim.x + threadIdx.x;
    const size_t strw = BUF_STRIDE_B / 8;
    if (gid < N_NODES) {
        int n = gid;
        // last occurrence of n in input_nodes (last-write-wins scatter semantics)
        int jm = -1;
        for (int j = 0; j < INPUT_BITS; ++j)
            if (input_nodes[j] == n) jm = j;
        uint64_t v = init_states[n] ? ~0ull : 0ull;   // same init for all 64 batches
        if (jm >= 0) {
            uint64_t m = 0ull;
            for (int b = 0; b < BATCH; ++b)
                m |= (uint64_t)(x[b * (T_STEPS * INPUT_BITS) + jm] & 1) << b;  // t = 0
            v ^= m;
        }
        bufs[n] = v;                                  // buf[0]
    } else if (gid < N_NODES + NBUF) {
        // zero sentinel word in every ring buffer (masked-off edges point here)
        bufs[(size_t)(gid - N_NODES) * strw + N_NODES] = 0ull;
    } else if (gid < N_NODES + NBUF + T_STEPS * INPUT_BITS) {
        int k = gid - (N_NODES + NBUF);
        int t = k >> 6, j = k & 63;
        uint64_t m = 0ull;
        for (int b = 0; b < BATCH; ++b)
            m |= (uint64_t)(x[b * (T_STEPS * INPUT_BITS) + t * INPUT_BITS + j] & 1) << b;
        xmask[k] = m;
    } else if (gid < N_NODES + NBUF + T_STEPS * INPUT_BITS + T_STEPS) {
        ctr[gid - (N_NODES + NBUF + T_STEPS * INPUT_BITS)] = 0;   // replay-safe
    }
}

// ---------------- pack LUT to bits (full-GPU, HBM-bound): 204.8 MB -> 6.4 MB ----------------
__global__ void lutpack_kernel(const int* __restrict__ lut,
                               uint64_t* __restrict__ plut) {
    const int tid = threadIdx.x;
    const int blk = blockIdx.x;                  // node
    const int lane = tid & 63, wave = tid >> 6;  // 16 waves x 64 lanes = 1024 entries
    int v = lut[(size_t)blk * 1024 + tid];
    uint64_t m = __ballot(v & 1);
    if (lane == 0) plut[(size_t)blk * 16 + wave] = m;
}

// ---------------- cooperative kernel: all 32 steps ----------------
__global__ __launch_bounds__(NTHR)
void reservoir_coop(const uint64_t* __restrict__ plut,
                    const int* __restrict__ adj,
                    const int* __restrict__ adjmask,
                    const int* __restrict__ input_nodes,
                    const uint64_t* __restrict__ xmask,
                    uint64_t* __restrict__ bufs,
                    uint32_t* __restrict__ ctr) {
    __shared__ uint8_t lutb[NPW * 128];   // 32 KB: this WG's 256 bit-packed LUT rows

    const int tid = threadIdx.x;
    const int wg  = blockIdx.x;

    // ---- stage packed LUT slice -> LDS (coalesced, 32 B/thread) ----
    {
        const uint4* src = (const uint4*)(plut + (size_t)wg * NPW * 16);
        uint4* dst = (uint4*)lutb;
        dst[tid * 2]     = src[tid * 2];
        dst[tid * 2 + 1] = src[tid * 2 + 1];
    }

    // ---- persistent per-thread setup (registers for all 32 steps) ----
    const int nl   = tid >> 2;            // local node
    const int q    = tid & 3;             // batch quarter (16 batches)
    const int node = wg * NPW + nl;
    const bool valid = node < N_NODES;
    const uint32_t qsh = (uint32_t)(q & 1) * 16;

    uint32_t off[K_MAX];                  // byte offsets of gather dwords (buffer-relative)
    uint32_t soff = 0;                    // store dword byte offset (even-q lanes)
    int jm = -1;
    if (valid) {
        #pragma unroll
        for (int k = 0; k < K_MAX; ++k) {
            int a  = adj[node * K_MAX + k];
            int mk = adjmask[node * K_MAX + k];
            // masked-off neighbor -> sentinel word N_NODES (always 0)
            off[k] = (uint32_t)(mk ? a : N_NODES) * 8u + (uint32_t)(q >> 1) * 4u;
        }
        for (int j = 0; j < INPUT_BITS; ++j)
            if (input_nodes[j] == node) jm = j;   // last occurrence
        soff = (uint32_t)node * 8u + (uint32_t)(q >> 1) * 4u;
    }
    const int rowbase = nl * 128;
    __syncthreads();                      // LDS staging complete

    for (int t = 0; t < T_STEPS; ++t) {
        // step t: read buf[t] (plain cached loads -- ring guarantees freshness),
        //         write buf[t+1] (agent-scope write-through).
        const char* src = (const char*)bufs + (size_t)t * BUF_STRIDE_B;
        char*       dst = (char*)bufs + (size_t)(t + 1) * BUF_STRIDE_B;
        if (valid) {
            uint32_t w[K_MAX];
            #pragma unroll
            for (int k = 0; k < K_MAX; ++k)
                w[k] = *(const uint32_t*)(src + off[k]) >> qsh;

            uint32_t o16 = 0;
            #pragma unroll
            for (int b = 0; b < 16; ++b) {
                uint32_t idx = 0;
                #pragma unroll
                for (int k = 0; k < K_MAX; ++k)
                    idx = (idx << 1) | ((w[k] >> b) & 1u);   // k=0 -> MSB (pow2 order)
                uint32_t d = *(const uint32_t*)(lutb + rowbase + ((idx >> 5) << 2));
                o16 |= ((d >> (idx & 31)) & 1u) << b;
            }

            // pair lanes (q even/odd) combine to one dword store
            uint32_t hi = __shfl_down(o16, 1);
            if ((q & 1) == 0) {
                uint32_t o32 = o16 | (hi << 16);
                // fold next step's input-bit XOR into this write
                if (jm >= 0 && t < T_STEPS - 1)
                    o32 ^= ((const uint32_t*)xmask)[((t + 1) * INPUT_BITS + jm) * 2 + (q >> 1)];
                __hip_atomic_store((uint32_t*)(dst + soff), o32,
                                   __ATOMIC_RELAXED, __HIP_MEMORY_SCOPE_AGENT);
            }
        }

        if (t < T_STEPS - 1) {
            // ---- global barrier: syncthreads drains vmcnt (sc1 stores are L3-visible),
            //      then 1 agent atomic + poll per WG. No cache maintenance needed. ----
            __syncthreads();
            if (tid == 0) {
                __hip_atomic_fetch_add(&ctr[t], 1u, __ATOMIC_RELAXED, __HIP_MEMORY_SCOPE_AGENT);
                while (__hip_atomic_load(&ctr[t], __ATOMIC_RELAXED, __HIP_MEMORY_SCOPE_AGENT)
                       < (uint32_t)NWG)
                    __builtin_amdgcn_s_sleep(2);
            }
            __syncthreads();
        }
    }
}

// ---------------- output: out[b,i] = sum_n state[b,n]*W[i,n] + bias[i] ----------------
__global__ void out_kernel(const uint64_t* __restrict__ fstate,
                           const float* __restrict__ W,
                           const float* __restrict__ bias,
                           float* __restrict__ out) {
    const int wg = blockIdx.x;          // b*16 + i
    const int b = wg >> 4, i = wg & 15;
    const int tid = threadIdx.x;
    const uint8_t* st = (const uint8_t*)fstate;
    const int byteoff = b >> 3, bsh = b & 7;

    float s = 0.f;
    for (int n = tid; n < N_NODES; n += 256) {
        uint32_t bit = (st[(size_t)n * 8 + byteoff] >> bsh) & 1u;
        s += (float)bit * W[(size_t)i * N_NODES + n];
    }
    #pragma unroll
    for (int off = 32; off; off >>= 1) s += __shfl_down(s, off);

    __shared__ float part[4];
    const int lane = tid & 63, wave = tid >> 6;
    if (lane == 0) part[wave] = s;
    __syncthreads();
    if (tid == 0) out[wg] = part[0] + part[1] + part[2] + part[3] + bias[i];
}

extern "C" void kernel_launch(void* const* d_in, const int* in_sizes, int n_in,
                              void* d_out, int out_size, void* d_ws, size_t ws_size,
                              hipStream_t stream) {
    const int*   x       = (const int*)d_in[0];
    const int*   adj     = (const int*)d_in[1];
    const int*   adjmask = (const int*)d_in[2];
    const int*   lut     = (const int*)d_in[3];
    const int*   initst  = (const int*)d_in[4];
    const int*   innodes = (const int*)d_in[5];
    const float* W       = (const float*)d_in[6];
    const float* bias    = (const float*)d_in[7];
    float* out = (float*)d_out;

    char* ws = (char*)d_ws;
    uint64_t* bufs  = (uint64_t*)(ws + OFF_BUFS);
    uint64_t* xmask = (uint64_t*)(ws + OFF_XMASK);
    uint32_t* ctr   = (uint32_t*)(ws + OFF_CTR);
    uint64_t* plut  = (uint64_t*)(ws + OFF_PLUT);

    {
        int prep_threads = N_NODES + NBUF + T_STEPS * INPUT_BITS + T_STEPS;
        int prep_blocks = (prep_threads + 255) / 256;
        hipLaunchKernelGGL(prep_kernel, dim3(prep_blocks), dim3(256), 0, stream,
                           x, initst, innodes, bufs, xmask, ctr);
    }

    hipLaunchKernelGGL(lutpack_kernel, dim3(N_NODES), dim3(1024), 0, stream, lut, plut);

    {
        void* args[] = { (void*)&plut, (void*)&adj, (void*)&adjmask, (void*)&innodes,
                         (void*)&xmask, (void*)&bufs, (void*)&ctr };
        hipLaunchCooperativeKernel((void*)reservoir_coop,
                                   dim3(NWG), dim3(NTHR),
                                   args, 0, stream);
    }

    // final states live in buf[32]
    hipLaunchKernelGGL(out_kernel, dim3(BATCH * N_INPUTS), dim3(256), 0, stream,
                       (const uint64_t*)(ws + OFF_BUFS + (size_t)T_STEPS * BUF_STRIDE_B),
                       W, bias, out);
}